// Round 9
// baseline (558.365 us; speedup 1.0000x reference)
//
#include <hip/hip_runtime.h>
#include <hip/hip_fp16.h>

// Problem constants
#define Bc  64
#define Sc  256
#define Icc 256
#define Hh  512
#define HW  1024   // 2*Hh

typedef float f32x2 __attribute__((ext_vector_type(2)));

__device__ __forceinline__ f32x2 splat2(float x) { return (f32x2){x, x}; }

__device__ __forceinline__ float fast_tanh(float x) {
  float e = __expf(2.0f * x);
  return 1.0f - 2.0f * __builtin_amdgcn_rcpf(e + 1.0f);
}

template <typename T>
__device__ __forceinline__ float ldf(const T* p) {
  if constexpr (sizeof(T) == 4) return *p;
  else return __half2float(*p);
}
template <typename T>
__device__ __forceinline__ void stf(T* p, float v) {
  if constexpr (sizeof(T) == 4) *p = v;
  else *p = __float2half(v);
}

// Cross-lane helpers (verified passing rounds 3-7).
template <int CTRL>
__device__ __forceinline__ float dpp_mov(float x) {
  return __int_as_float(
      __builtin_amdgcn_update_dpp(0, __float_as_int(x), CTRL, 0xF, 0xF, true));
}
template <int CTRL>
__device__ __forceinline__ float dpp_add(float x) {
  return x + dpp_mov<CTRL>(x);
}
template <int XMASK>
__device__ __forceinline__ float swz_add(float x) {
  int y = __builtin_amdgcn_ds_swizzle(__float_as_int(x), (XMASK << 10) | 0x1F);
  return x + __int_as_float(y);
}
// quad_perm(1,0,3,2)=0xB1 (xor1), quad_perm(2,3,0,1)=0x4E (xor2),
// row_ror:8=0x128 (xor8 within 16), quad bcast i = {0x00,0x55,0xAA,0xFF}

constexpr float ALPHA = 0.90483741803595957f;  // exp(-1/10)
constexpr float DT    = 0.95122942450071400f;  // exp(-1/20)
constexpr float OMD   = 0.04877057549928599f;  // 1 - DT
constexpr float LR_   = 0.01f;

// ---------------- GEMM: I[m][h] = sum_k X[m][k] * W[h][k] ----------------
// M=16384, N=1024, K=256. 128x64 tile, 256 threads, 8x4 per thread.
// Known-good (round-7 verified, ~150 us). MFMA variant was tried (round 8)
// and REJECTED: bf16 hi/lo splits floor at ~3e-5 If error, and the scan's
// nonlinear feedback amplifies If noise ~1e3-1e4x -> vals failed at 0.16.
// The scan requires near-fp32 If; keep the vector GEMM.
template <typename T>
__global__ __launch_bounds__(256, 2) void gemm_xw(const float* __restrict__ X,
                                                  const float* __restrict__ Wm,
                                                  T* __restrict__ Out) {
  __shared__ float As[16][132];  // [k][m], pad 4
  __shared__ float Bs[16][68];   // [k][n], pad 4
  const int tid = threadIdx.x;
  const int m0 = blockIdx.x << 7;
  const int n0 = blockIdx.y << 6;
  const int tx4 = (tid & 15) << 2;
  const int ty4 = (tid >> 4) << 2;
  const int lr = tid >> 2;
  const int lk = (tid & 3) << 2;

  f32x2 acc2[8][2];
#pragma unroll
  for (int i = 0; i < 8; ++i) {
    acc2[i][0] = (f32x2){0.f, 0.f};
    acc2[i][1] = (f32x2){0.f, 0.f};
  }

  const float* xg0 = X + (size_t)(m0 + lr) * Icc + lk;
  const float* xg1 = X + (size_t)(m0 + 64 + lr) * Icc + lk;
  const float* wg  = Wm + (size_t)(n0 + lr) * Icc + lk;

  for (int k0 = 0; k0 < Icc; k0 += 16) {
    float4 a0 = *(const float4*)(xg0 + k0);
    float4 a1 = *(const float4*)(xg1 + k0);
    float4 bv = *(const float4*)(wg + k0);
    __syncthreads();
    As[lk + 0][lr] = a0.x; As[lk + 1][lr] = a0.y;
    As[lk + 2][lr] = a0.z; As[lk + 3][lr] = a0.w;
    As[lk + 0][lr + 64] = a1.x; As[lk + 1][lr + 64] = a1.y;
    As[lk + 2][lr + 64] = a1.z; As[lk + 3][lr + 64] = a1.w;
    Bs[lk + 0][lr] = bv.x; Bs[lk + 1][lr] = bv.y;
    Bs[lk + 2][lr] = bv.z; Bs[lk + 3][lr] = bv.w;
    __syncthreads();
#pragma unroll
    for (int kk = 0; kk < 16; ++kk) {
      float a[8];
      f32x2 b2[2];
      *(float4*)&a[0] = *(const float4*)&As[kk][ty4];
      *(float4*)&a[4] = *(const float4*)&As[kk][ty4 + 64];
      *(float4*)&b2[0] = *(const float4*)&Bs[kk][tx4];
#pragma unroll
      for (int i = 0; i < 8; ++i) {
        f32x2 aa = splat2(a[i]);
        acc2[i][0] += aa * b2[0];
        acc2[i][1] += aa * b2[1];
      }
    }
  }
#pragma unroll
  for (int i = 0; i < 8; ++i) {
    const int mrow = m0 + ((i < 4) ? (ty4 + i) : (64 + ty4 + i - 4));
    T* op = Out + (size_t)mrow * HW + n0 + tx4;
    if constexpr (sizeof(T) == 4) {
      *(float4*)op = make_float4(acc2[i][0].x, acc2[i][0].y, acc2[i][1].x, acc2[i][1].y);
    } else {
      stf(op + 0, acc2[i][0].x); stf(op + 1, acc2[i][0].y);
      stf(op + 2, acc2[i][1].x); stf(op + 3, acc2[i][1].y);
    }
  }
}

// ---------------- Scan (round-7 verified structure + XCD-local swizzle) ----
// Flat id remap: b = (fid&7) + 8*(fid>>7), rb = (fid>>3)&15. Bijective pure
// relabel (bits 0-2 -> b-low, 3-6 -> rb, 7-9 -> b-high): identical arithmetic
// and write addresses -> outputs BIT-IDENTICAL to round 7. All 16 row-blocks
// of a batch get the same fid%8 -> same XCD -> the shared per-batch ik/iv
// stream (4MB If slice) is one L2's working set instead of 8 XCDs missing
// independently (FETCH_SIZE 149MB round 7).
//
// Scaled-memory: mem(t) = A_row(t) * M~(t); update M~ += (c*invA*OMD) * K~
// -> ONE pk-fma per element pair. Every 16 steps A_row folds into M~
// (caps invA <= 1.175; round-6 precision lesson). kt in registers as
// K~ = kt/OMD (one pk-fma); OMD folds into broadcast c~. Reduce-scatter
// butterfly: lane L owns row L&3's sum (bitwise-identical across lanes);
// v-recurrence once per row; c~ broadcast with 4 DPP movs. ONE barrier/step.
template <typename T>
__global__ __launch_bounds__(256, 4) void scan_kernel(const T* __restrict__ If,
                                                      float* __restrict__ mem_out,
                                                      float* __restrict__ keys,
                                                      float* __restrict__ vals) {
  const int fid = blockIdx.x + (blockIdx.y << 4);  // gridDim.x == 16
  const int b  = (fid & 7) + ((fid >> 7) << 3);
  const int rb = (fid >> 3) & 15;
  const int tid = threadIdx.x;
  const int ch = tid & 31;   // col chunk 0..31
  const int g = tid >> 5;    // row group 0..7
  const int r0 = rb << 5;
  const int row0 = r0 + (g << 2);  // first of this thread's 4 rows
  const int ri = ch & 3;           // row this lane owns after scatter

  __shared__ float k_s[2][640];    // 32 chunks x 20 floats, double-buffered

  f32x2 mem2[32];  // M~ : [i*8+jj] row row0+i, cols 16*ch + 2*jj, 2*jj+1
#pragma unroll
  for (int j = 0; j < 32; ++j) mem2[j] = (f32x2){0.f, 0.f};
  f32x2 kt2[8];    // K~ = kt/OMD for own 16 columns
#pragma unroll
  for (int j = 0; j < 8; ++j) kt2[j] = (f32x2){0.f, 0.f};
  float kss0 = 0.f, kss1 = 0.f;    // k-chain state (2 channels)
  float vs = 0.f, vt = 0.f;        // own row's v-chain
  float Arow = 1.f, invA = 1.f;    // running decay product + inverse

  const int h0 = 2 * tid;                                  // owned channels
  const int sidx = (tid >> 3) * 20 + (h0 & 15);            // staging index
  const T* ikp = If + (size_t)b * Sc * HW + h0;            // ik source
  const T* ivp = If + (size_t)b * Sc * HW + 512 + row0 + ri;  // own-row iv
  float* keysb = keys + (size_t)b * Sc * Hh;
  float* valsb = vals + (size_t)b * Sc * Hh + row0;

  const bool sb0 = (ch & 1) != 0;  // scatter-stage selects (loop-invariant)
  const bool sb1 = (ch & 2) != 0;

  // prefetch t=0 inputs
  float ik0, ik1, ivc;
  {
    if constexpr (sizeof(T) == 4) {
      float2 v2 = *(const float2*)ikp;
      ik0 = v2.x; ik1 = v2.y;
    } else {
      float2 v2 = __half22float2(*(const __half2*)ikp);
      ik0 = v2.x; ik1 = v2.y;
    }
    ivc = ldf(ivp);
  }

  for (int t = 0; t < Sc; ++t) {
    const int buf = t & 1;

    // ---- phase 1: k-chain update for own 2 channels, stage k to LDS ----
    const float cik0 = ik0, cik1 = ik1;
    const float civ = ivc;
    {  // prefetch t+1 (clamped)
      const size_t tn = (size_t)((t + 1 < Sc) ? t + 1 : t) * HW;
      if constexpr (sizeof(T) == 4) {
        float2 v2 = *(const float2*)(ikp + tn);
        ik0 = v2.x; ik1 = v2.y;
      } else {
        float2 v2 = __half22float2(*(const __half2*)(ikp + tn));
        ik0 = v2.x; ik1 = v2.y;
      }
      ivc = ldf(ivp + tn);
    }
    kss0 = ALPHA * kss0 + cik0;
    kss1 = ALPHA * kss1 + cik1;
    float k0 = fast_tanh(kss0);
    float k1 = fast_tanh(kss1);
    *(float2*)&k_s[buf][sidx] = make_float2(k0, k1);
    if (rb == 0) {
      *(float2*)&keysb[(size_t)t * Hh + h0] = make_float2(k0, k1);
    }
    __syncthreads();  // the only barrier per step

    // ---- load own 16 k values ----
    f32x2 kv2[8];
    {
      const float4* kc = (const float4*)&k_s[buf][ch * 20];
#pragma unroll
      for (int q = 0; q < 4; ++q) {
        float4 kq = kc[q];
        kv2[2 * q + 0] = (f32x2){kq.x, kq.y};
        kv2[2 * q + 1] = (f32x2){kq.z, kq.w};
      }
    }

    // ---- phase 2: matvec partials (32 pk-fma) ----
    f32x2 acc2[4];
#pragma unroll
    for (int i = 0; i < 4; ++i) acc2[i] = (f32x2){0.f, 0.f};
#pragma unroll
    for (int jj = 0; jj < 8; ++jj) {
      const f32x2 kv = kv2[jj];
      acc2[0] += mem2[jj] * kv;
      acc2[1] += mem2[8 + jj] * kv;
      acc2[2] += mem2[16 + jj] * kv;
      acc2[3] += mem2[24 + jj] * kv;
    }
    float p0 = acc2[0].x + acc2[0].y;
    float p1 = acc2[1].x + acc2[1].y;
    float p2 = acc2[2].x + acc2[2].y;
    float p3 = acc2[3].x + acc2[3].y;

    // ---- K~ trace update (8 pk-fma): K~ = DT*K~ + k ----
#pragma unroll
    for (int jj = 0; jj < 8; ++jj)
      kt2[jj] = kt2[jj] * splat2(DT) + kv2[jj];

    // ---- reduce-scatter; lane L ends with row L&3's raw sum ----
    // (xor-butterfly: all 8 lane-copies of a row's sum are bitwise
    //  identical -- required, the v-chain is redundantly computed)
    float x  = sb0 ? p0 : p1;
    float y  = sb0 ? p2 : p3;
    float o0 = sb0 ? p1 : p0;
    float o1 = sb0 ? p3 : p2;
    float q0 = o0 + dpp_mov<0xB1>(x);
    float q1 = o1 + dpp_mov<0xB1>(y);
    float x2 = sb1 ? q0 : q1;
    float o2 = sb1 ? q1 : q0;
    float s = o2 + dpp_mov<0x4E>(x2);
    s = swz_add<4>(s);
    s = dpp_add<0x128>(s);
    s = swz_add<16>(s);
    s *= Arow;  // unscale: p_true = A_row * (M~ . k)

    // ---- phase 3: v-recurrence for the ONE owned row ----
    vs = fmaf(ALPHA, vs, fmaf(0.2f, s, civ));
    float v = fast_tanh(vs);
    vt = fmaf(DT, vt, OMD * v);
    float a_own = fmaf(-LR_ * vt, vt, 1.0f);
    float c_own = LR_ * vt;
    Arow *= a_own;
    float r = __builtin_amdgcn_rcpf(a_own);
    r = r * fmaf(-a_own, r, 2.0f);   // Newton step
    invA *= r;
    float ct_own = c_own * invA * OMD;  // c~ (OMD folds K~ back to kt)
    if (ch < 4) {
      valsb[(size_t)t * Hh + ch] = v;  // lanes 0..3 hold rows 0..3
    }
    float ct0 = dpp_mov<0x00>(ct_own), ct1 = dpp_mov<0x55>(ct_own);
    float ct2 = dpp_mov<0xAA>(ct_own), ct3 = dpp_mov<0xFF>(ct_own);

    // ---- phase 4: scaled rank-1 update (32 pk-fma): M~ += c~ * K~ ----
    {
      const f32x2 cc0 = splat2(ct0), cc1 = splat2(ct1);
      const f32x2 cc2 = splat2(ct2), cc3 = splat2(ct3);
#pragma unroll
      for (int jj = 0; jj < 8; ++jj) {
        const f32x2 kt = kt2[jj];
        mem2[jj]      += cc0 * kt;
        mem2[8 + jj]  += cc1 * kt;
        mem2[16 + jj] += cc2 * kt;
        mem2[24 + jj] += cc3 * kt;
      }
    }

    // ---- chunked rescale: every 16 steps fold A_row into M~ ----
    if ((t & 15) == 15) {
      float f0 = dpp_mov<0x00>(Arow), f1 = dpp_mov<0x55>(Arow);
      float f2 = dpp_mov<0xAA>(Arow), f3 = dpp_mov<0xFF>(Arow);
      const f32x2 s0 = splat2(f0), s1 = splat2(f1);
      const f32x2 s2 = splat2(f2), s3 = splat2(f3);
#pragma unroll
      for (int jj = 0; jj < 8; ++jj) {
        mem2[jj]      *= s0;
        mem2[8 + jj]  *= s1;
        mem2[16 + jj] *= s2;
        mem2[24 + jj] *= s3;
      }
      Arow = 1.f;
      invA = 1.f;
    }
  }

  // epilogue: write mem (Sc%16==0 -> last fold already applied, Arow==1)
#pragma unroll
  for (int i = 0; i < 4; ++i) {
    float* mb = mem_out + (size_t)b * Hh * Hh + (size_t)(row0 + i) * Hh + (ch << 4);
#pragma unroll
    for (int q = 0; q < 4; ++q) {
      f32x2 lo = mem2[i * 8 + 2 * q];
      f32x2 hi = mem2[i * 8 + 2 * q + 1];
      *(float4*)(mb + 4 * q) = make_float4(lo.x, lo.y, hi.x, hi.y);
    }
  }
}

extern "C" void kernel_launch(void* const* d_in, const int* in_sizes, int n_in,
                              void* d_out, int out_size, void* d_ws, size_t ws_size,
                              hipStream_t stream) {
  const float* x = (const float*)d_in[0];   // (64,256,256) fp32
  const float* W = (const float*)d_in[1];   // (1024,256) fp32
  float* out = (float*)d_out;
  float* mem_out = out;                          // 16,777,216 floats
  float* keys    = out + 16777216;               //  8,388,608 floats
  float* vals    = out + 25165824;               //  8,388,608 floats

  const dim3 gemm_grid(128, 16), gemm_blk(256);
  const dim3 scan_grid(16, 64),  scan_blk(256);
  const size_t i_elems = (size_t)Bc * Sc * HW;   // 16,777,216

  if (ws_size >= i_elems * sizeof(float)) {
    float* If = (float*)d_ws;
    gemm_xw<float><<<gemm_grid, gemm_blk, 0, stream>>>(x, W, If);
    scan_kernel<float><<<scan_grid, scan_blk, 0, stream>>>(If, mem_out, keys, vals);
  } else {
    __half* If = (__half*)d_ws;
    gemm_xw<__half><<<gemm_grid, gemm_blk, 0, stream>>>(x, W, If);
    scan_kernel<__half><<<scan_grid, scan_blk, 0, stream>>>(If, mem_out, keys, vals);
  }
}